// Round 3
// baseline (536.491 us; speedup 1.0000x reference)
//
#include <hip/hip_runtime.h>

// ============================================================================
// Fused 2-layer transformer encoder (B=1024, T=128, D=128, H=8, HD=16, FF=512)
// One workgroup per batch element; bf16 MFMA 16x16x32 for every matmul; fp32
// accumulation/softmax/LN. All matmuls in transposed orientation (Y^T = W*X^T)
// so C-fragments pack as ushort4 column runs.
//
// Occupancy revision: LDS cut 146 KiB -> 73 KiB so 2 blocks/CU (4 waves/SIMD)
// fit, with VGPR pinned to 128 via __launch_bounds__(512,4).
//  - K and V never touch LDS: the producer C-layout -> consumer A-fragment
//    mismatch is a same-l15 cross-kg permutation, done with __shfl
//    (ds_bpermute) on bf16-packed dwords. Phase A is split into Q+K and V
//    passes to bound register pressure.
//  - P -> PV handoff uses the same shuffle gather (P scratch deleted, along
//    with its two serializing lgkmcnt(0) points per q-tile).
//  - FF hidden aliases the q/o buffer (4 chunks of 128).
//  - softmax uses __expf (proven on this toolchain in earlier rounds).
// ============================================================================

typedef __attribute__((ext_vector_type(8))) __bf16 bf16x8;
typedef __attribute__((ext_vector_type(4))) float fx4;

#define MFMA16(a, b, c) __builtin_amdgcn_mfma_f32_16x16x32_bf16((a), (b), (c), 0, 0, 0)

static __device__ __forceinline__ unsigned short f2bf(float f) {
    __bf16 b = (__bf16)f;                       // fptrunc f32->bf16, RTN-even
    return __builtin_bit_cast(unsigned short, b);
}
static __device__ __forceinline__ float bf2f(unsigned short u) {
    return (float)__builtin_bit_cast(__bf16, u);
}
static __device__ __forceinline__ unsigned pk2(float a, float b) {
    return (unsigned)f2bf(a) | ((unsigned)f2bf(b) << 16);
}
static __device__ __forceinline__ bf16x8 mk8(unsigned d0, unsigned d1,
                                             unsigned d2, unsigned d3) {
    union { unsigned u[4]; bf16x8 v; } c;
    c.u[0] = d0; c.u[1] = d1; c.u[2] = d2; c.u[3] = d3;
    return c.v;
}
// element index into a [128][128] tile, 16B-unit XOR swizzle on the row
static __device__ __forceinline__ int swz(int row, int col) {
    return (row << 7) + (col ^ ((row & 7) << 3));
}

// --------------------------------------------------------------------------
// Prep: convert all fp32 weights to bf16 into workspace.
// Segments (elements): in_proj 98304 | out 32768 | ff1 131072 | ff2 131072
// --------------------------------------------------------------------------
extern "C" __global__ void prep_weights_bf16(const float* __restrict__ w_in,
                                             const float* __restrict__ w_out,
                                             const float* __restrict__ w_ff1,
                                             const float* __restrict__ w_ff2,
                                             unsigned short* __restrict__ ws) {
    int i = blockIdx.x * 256 + threadIdx.x;     // grid covers exactly 393216
    float v;
    if (i < 98304)       v = w_in[i];
    else if (i < 131072) v = w_out[i - 98304];
    else if (i < 262144) v = w_ff1[i - 131072];
    else                 v = w_ff2[i - 262144];
    ws[i] = f2bf(v);
}

// --------------------------------------------------------------------------
// Main fused kernel. block = 512 threads = 8 waves. grid = 1024 (one per b).
// __launch_bounds__(512, 4): 4 waves/EU -> 2 blocks/CU; VGPR capped at 128.
// --------------------------------------------------------------------------
extern "C" __global__ void __launch_bounds__(512, 4)
fused_transformer(const float* __restrict__ x,
                  const float* __restrict__ mask,
                  const float* __restrict__ inp_b,
                  const float* __restrict__ out_b,
                  const float* __restrict__ ln1g, const float* __restrict__ ln1b,
                  const float* __restrict__ ff1b, const float* __restrict__ ff2b,
                  const float* __restrict__ ln2g, const float* __restrict__ ln2b,
                  const unsigned short* __restrict__ w_inp,
                  const unsigned short* __restrict__ w_out,
                  const unsigned short* __restrict__ w_ff1,
                  const unsigned short* __restrict__ w_ff2,
                  float* __restrict__ out) {
    // 73 KiB static LDS -> 2 blocks/CU
    __shared__ __align__(16) unsigned short xs[16384];   // x / LN outputs [t][d]
    __shared__ __align__(16) unsigned short qs[16384];   // q -> o -> FF hidden
    __shared__ __align__(16) float lnbuf[2304];          // LN scratch, 9 KiB

    float2* lnp = (float2*)lnbuf;          // [8][128] {sum, sumsq}
    float2* mrp = lnp + 1024;              // [128] {mean, rstd}

    const int tid = threadIdx.x;
    const int w   = tid >> 6;        // wave 0..7 (== head in phase B)
    const int lid = tid & 63;
    const int l15 = lid & 15;
    const int kg  = lid >> 4;        // k-group 0..3
    const int b   = blockIdx.x;

    // ---- stage x[b] (fp32 global) -> xs (bf16 LDS, swizzled) ----
    const float* xb = x + (size_t)b * 16384;
    #pragma unroll
    for (int i = 0; i < 8; ++i) {
        int e = i * 2048 + tid * 4;
        float4 v4 = *(const float4*)(xb + e);
        int row = e >> 7, col = e & 127;
        ushort4 pk;
        pk.x = f2bf(v4.x); pk.y = f2bf(v4.y); pk.z = f2bf(v4.z); pk.w = f2bf(v4.w);
        *(ushort4*)(xs + swz(row, col)) = pk;
    }
    // additive key mask, key = nt*16 + l15 (per-lane, reused for both layers)
    float mreg[8];
    #pragma unroll
    for (int nt = 0; nt < 8; ++nt) mreg[nt] = mask[b * 128 + nt * 16 + l15];

    __syncthreads();

    for (int l = 0; l < 2; ++l) {
        bf16x8 kfr[8];   // K A-fragments for this wave's head (+mask slot)
        bf16x8 vfr[4];   // V^T A-fragments

        // ========== Phase A: QKV projection, K/V straight to registers =====
        {
            const unsigned short* wbase = w_inp + (size_t)l * 49152;
            // ---- pass 1: Q + K ----
            {
                bf16x8 wq[4], wk[4];
                #pragma unroll
                for (int ks = 0; ks < 4; ++ks) {
                    wq[ks] = *(const bf16x8*)(wbase + (w * 16 + l15) * 128 + ks * 32 + kg * 8);
                    wk[ks] = *(const bf16x8*)(wbase + (128 + w * 16 + l15) * 128 + ks * 32 + kg * 8);
                }
                fx4 bq = *(const fx4*)(inp_b + l * 384 + w * 16 + kg * 4);
                fx4 bk = *(const fx4*)(inp_b + l * 384 + 128 + w * 16 + kg * 4);
                const int sk = ((2 * kg) & 3) * 16 + l15;   // gather src (kg<2 valid)
                #pragma unroll
                for (int mt = 0; mt < 8; ++mt) {
                    int trow = mt * 16 + l15;
                    bf16x8 xf[4];
                    #pragma unroll
                    for (int ks = 0; ks < 4; ++ks)
                        xf[ks] = *(const bf16x8*)(xs + swz(trow, ks * 32 + kg * 8));
                    fx4 aq = bq, ak = bk;
                    #pragma unroll
                    for (int ks = 0; ks < 4; ++ks) {
                        aq = MFMA16(wq[ks], xf[ks], aq);   // Q^T = Wq * X^T
                        ak = MFMA16(wk[ks], xf[ks], ak);   // K^T = Wk * X^T
                    }
                    ushort4 pq;  // q pre-scaled by 1/sqrt(HD) = 0.25 (exact in bf16)
                    pq.x = f2bf(aq[0] * 0.25f); pq.y = f2bf(aq[1] * 0.25f);
                    pq.z = f2bf(aq[2] * 0.25f); pq.w = f2bf(aq[3] * 0.25f);
                    *(ushort4*)(qs + swz(trow, w * 16 + kg * 4)) = pq;
                    // K: pack 4 f32 -> 2 bf16-pair dwords, cross-kg gather
                    unsigned p0 = pk2(ak[0], ak[1]), p1 = pk2(ak[2], ak[3]);
                    unsigned d0 = __shfl(p0, sk, 64),      d1 = __shfl(p1, sk, 64);
                    unsigned d2 = __shfl(p0, sk + 16, 64), d3 = __shfl(p1, sk + 16, 64);
                    if (kg == 2)      { bf16x8 f = {}; f[0] = (__bf16)mreg[mt]; kfr[mt] = f; }
                    else if (kg == 3) { bf16x8 f = {}; kfr[mt] = f; }
                    else              kfr[mt] = mk8(d0, d1, d2, d3);
                }
            }
            // ---- pass 2: V ----
            {
                bf16x8 wv[4];
                #pragma unroll
                for (int ks = 0; ks < 4; ++ks)
                    wv[ks] = *(const bf16x8*)(wbase + (256 + w * 16 + l15) * 128 + ks * 32 + kg * 8);
                float bv = inp_b[l * 384 + 256 + w * 16 + l15];
                const int sv = (2 * (kg & 1)) * 16 + l15;
                #pragma unroll
                for (int mt = 0; mt < 8; ++mt) {
                    int trow = mt * 16 + l15;
                    bf16x8 xf[4];
                    #pragma unroll
                    for (int ks = 0; ks < 4; ++ks)
                        xf[ks] = *(const bf16x8*)(xs + swz(trow, ks * 32 + kg * 8));
                    fx4 av = {bv, bv, bv, bv};
                    #pragma unroll
                    for (int ks = 0; ks < 4; ++ks)
                        av = MFMA16(xf[ks], wv[ks], av);   // V = X * Wv^T
                    unsigned p0 = pk2(av[0], av[1]), p1 = pk2(av[2], av[3]);
                    unsigned d0 = __shfl(p0, sv, 64),      d1 = __shfl(p1, sv, 64);
                    unsigned d2 = __shfl(p0, sv + 16, 64), d3 = __shfl(p1, sv + 16, 64);
                    if ((kg >> 1) == (mt & 1)) vfr[mt >> 1] = mk8(d0, d1, d2, d3);
                }
            }
        }
        // own-wave q write -> read; drain DS queue (no cross-wave dependency)
        asm volatile("s_waitcnt lgkmcnt(0)" ::: "memory");

        // ========== Phase B: attention, wave w == head h (no barriers) ======
        {
            const int h = w;
            const int sp = (2 * (kg & 1)) * 16 + l15;   // P gather src base
            for (int qt = 0; qt < 8; ++qt) {
                int qrow = qt * 16 + l15;
                bf16x8 qf = {};
                if (kg < 2) qf = *(const bf16x8*)(qs + swz(qrow, h * 16 + kg * 8));
                else if (kg == 2) qf[0] = (__bf16)1.0f;   // ones column -> adds mask
                // S^T tile: lane l15 = query, 32 regs = keys (scaled+masked)
                fx4 sc[8];
                #pragma unroll
                for (int kt = 0; kt < 8; ++kt) {
                    fx4 z = {0.f, 0.f, 0.f, 0.f};
                    sc[kt] = MFMA16(kfr[kt], qf, z);
                }
                // per-lane softmax over 32 regs + 2 shuffles across kg
                float mx = -3.0e38f;
                #pragma unroll
                for (int kt = 0; kt < 8; ++kt)
                    #pragma unroll
                    for (int r = 0; r < 4; ++r) mx = fmaxf(mx, sc[kt][r]);
                mx = fmaxf(mx, __shfl_xor(mx, 16, 64));
                mx = fmaxf(mx, __shfl_xor(mx, 32, 64));
                float sm = 0.f;
                #pragma unroll
                for (int kt = 0; kt < 8; ++kt)
                    #pragma unroll
                    for (int r = 0; r < 4; ++r) {
                        float e = __expf(sc[kt][r] - mx);
                        sc[kt][r] = e;
                        sm += e;
                    }
                sm += __shfl_xor(sm, 16, 64);
                sm += __shfl_xor(sm, 32, 64);
                float inv = 1.f / sm;
                // PV: per 32-key step, gather P^T fragment via 8 shuffles
                fx4 oacc = {0.f, 0.f, 0.f, 0.f};
                #pragma unroll
                for (int s = 0; s < 4; ++s) {
                    unsigned pA0 = pk2(sc[2*s][0] * inv,   sc[2*s][1] * inv);
                    unsigned pA1 = pk2(sc[2*s][2] * inv,   sc[2*s][3] * inv);
                    unsigned pB0 = pk2(sc[2*s+1][0] * inv, sc[2*s+1][1] * inv);
                    unsigned pB1 = pk2(sc[2*s+1][2] * inv, sc[2*s+1][3] * inv);
                    unsigned a0 = __shfl(pA0, sp, 64),      a1 = __shfl(pA1, sp, 64);
                    unsigned a2 = __shfl(pA0, sp + 16, 64), a3 = __shfl(pA1, sp + 16, 64);
                    unsigned b0 = __shfl(pB0, sp, 64),      b1 = __shfl(pB1, sp, 64);
                    unsigned b2 = __shfl(pB0, sp + 16, 64), b3 = __shfl(pB1, sp + 16, 64);
                    bf16x8 pf = (kg & 2) ? mk8(b0, b1, b2, b3) : mk8(a0, a1, a2, a3);
                    oacc = MFMA16(vfr[s], pf, oacc);        // O^T = V^T * P^T
                }
                // o tile packs as [t][d] ushort4; overwrites q cols of this qt
                ushort4 po;
                po.x = f2bf(oacc[0]); po.y = f2bf(oacc[1]);
                po.z = f2bf(oacc[2]); po.w = f2bf(oacc[3]);
                *(ushort4*)(qs + swz(qrow, h * 16 + kg * 4)) = po;
            }
        }
        __syncthreads();

        // ========= Phase C: out-proj (transposed) + residual + LN1 ==========
        {
            bf16x8 wof[4];
            #pragma unroll
            for (int ks = 0; ks < 4; ++ks)
                wof[ks] = *(const bf16x8*)(w_out + (size_t)(l * 128 + w * 16 + l15) * 128
                                           + ks * 32 + kg * 8);
            fx4 ob4 = *(const fx4*)(out_b + l * 128 + w * 16 + kg * 4);
            fx4 acc[8];
            #pragma unroll
            for (int tt = 0; tt < 8; ++tt) {
                int trow = tt * 16 + l15;
                fx4 a = {0.f, 0.f, 0.f, 0.f};
                #pragma unroll
                for (int ks = 0; ks < 4; ++ks) {
                    bf16x8 of = *(const bf16x8*)(qs + swz(trow, ks * 32 + kg * 8));
                    a = MFMA16(wof[ks], of, a);     // OUT^T = Wout * O^T
                }
                ushort4 rx = *(const ushort4*)(xs + swz(trow, w * 16 + kg * 4));
                a[0] += ob4[0] + bf2f(rx.x); a[1] += ob4[1] + bf2f(rx.y);
                a[2] += ob4[2] + bf2f(rx.z); a[3] += ob4[3] + bf2f(rx.w);
                acc[tt] = a;
                float s  = a[0] + a[1] + a[2] + a[3];
                float qq = a[0]*a[0] + a[1]*a[1] + a[2]*a[2] + a[3]*a[3];
                s  += __shfl_xor(s, 16, 64);  qq += __shfl_xor(qq, 16, 64);
                s  += __shfl_xor(s, 32, 64);  qq += __shfl_xor(qq, 32, 64);
                if (lid < 16) { float2 p; p.x = s; p.y = qq; lnp[w * 128 + trow] = p; }
            }
            __syncthreads();
            if (tid < 128) {
                float ms = 0.f, mq = 0.f;
                #pragma unroll
                for (int wv = 0; wv < 8; ++wv) {
                    float2 p = lnp[wv * 128 + tid];
                    ms += p.x; mq += p.y;
                }
                float mean = ms * 0.0078125f;
                float var  = mq * 0.0078125f - mean * mean;
                float2 m2; m2.x = mean; m2.y = rsqrtf(var + 1e-5f);
                mrp[tid] = m2;
            }
            __syncthreads();
            fx4 g4 = *(const fx4*)(ln1g + l * 128 + w * 16 + kg * 4);
            fx4 b4 = *(const fx4*)(ln1b + l * 128 + w * 16 + kg * 4);
            #pragma unroll
            for (int tt = 0; tt < 8; ++tt) {
                int trow = tt * 16 + l15;
                float2 m2 = mrp[trow];
                ushort4 px;
                px.x = f2bf((acc[tt][0] - m2.x) * m2.y * g4[0] + b4[0]);
                px.y = f2bf((acc[tt][1] - m2.x) * m2.y * g4[1] + b4[1]);
                px.z = f2bf((acc[tt][2] - m2.x) * m2.y * g4[2] + b4[2]);
                px.w = f2bf((acc[tt][3] - m2.x) * m2.y * g4[3] + b4[3]);
                *(ushort4*)(xs + swz(trow, w * 16 + kg * 4)) = px;
            }
        }
        __syncthreads();

        // ======== Phase D: FF, 4 K-chunks of 128; hidden aliases qs =========
        fx4 yacc[8];
        {
            fx4 z = {0.f, 0.f, 0.f, 0.f};
            #pragma unroll
            for (int tt = 0; tt < 8; ++tt) yacc[tt] = z;
        }
        #pragma unroll 1
        for (int c = 0; c < 4; ++c) {
            {   // FF1: H^T = W1 * X^T, + bias + relu -> qs (packed)
                bf16x8 w1f[4];
                int frow = l * 512 + c * 128 + w * 16;
                #pragma unroll
                for (int ks = 0; ks < 4; ++ks)
                    w1f[ks] = *(const bf16x8*)(w_ff1 + (size_t)(frow + l15) * 128
                                               + ks * 32 + kg * 8);
                fx4 b1f = *(const fx4*)(ff1b + frow + kg * 4);
                #pragma unroll
                for (int tt = 0; tt < 8; ++tt) {
                    int trow = tt * 16 + l15;
                    bf16x8 xf[4];
                    #pragma unroll
                    for (int ks = 0; ks < 4; ++ks)
                        xf[ks] = *(const bf16x8*)(xs + swz(trow, ks * 32 + kg * 8));
                    fx4 a = b1f;
                    #pragma unroll
                    for (int ks = 0; ks < 4; ++ks)
                        a = MFMA16(w1f[ks], xf[ks], a);
                    ushort4 ph;
                    ph.x = f2bf(fmaxf(a[0], 0.f)); ph.y = f2bf(fmaxf(a[1], 0.f));
                    ph.z = f2bf(fmaxf(a[2], 0.f)); ph.w = f2bf(fmaxf(a[3], 0.f));
                    *(ushort4*)(qs + swz(trow, w * 16 + kg * 4)) = ph;
                }
            }
            __syncthreads();
            {   // FF2 partial accumulate: Y^T = W2 * H^T
                bf16x8 w2f[4];
                #pragma unroll
                for (int k8 = 0; k8 < 4; ++k8)
                    w2f[k8] = *(const bf16x8*)(w_ff2 + (size_t)(l * 128 + w * 16 + l15) * 512
                                               + c * 128 + k8 * 32 + kg * 8);
                #pragma unroll
                for (int tt = 0; tt < 8; ++tt) {
                    int trow = tt * 16 + l15;
                    #pragma unroll
                    for (int k8 = 0; k8 < 4; ++k8) {
                        bf16x8 hf = *(const bf16x8*)(qs + swz(trow, k8 * 32 + kg * 8));
                        yacc[tt] = MFMA16(w2f[k8], hf, yacc[tt]);
                    }
                }
            }
            if (c < 3) __syncthreads();   // protect hidden before next chunk
        }

        // ========= Phase E: + bias + residual + LayerNorm2 (+ output) =======
        {
            fx4 fb4 = *(const fx4*)(ff2b + l * 128 + w * 16 + kg * 4);
            #pragma unroll
            for (int tt = 0; tt < 8; ++tt) {
                int trow = tt * 16 + l15;
                ushort4 rx = *(const ushort4*)(xs + swz(trow, w * 16 + kg * 4));
                yacc[tt][0] += fb4[0] + bf2f(rx.x);
                yacc[tt][1] += fb4[1] + bf2f(rx.y);
                yacc[tt][2] += fb4[2] + bf2f(rx.z);
                yacc[tt][3] += fb4[3] + bf2f(rx.w);
                fx4 a = yacc[tt];
                float s  = a[0] + a[1] + a[2] + a[3];
                float qq = a[0]*a[0] + a[1]*a[1] + a[2]*a[2] + a[3]*a[3];
                s  += __shfl_xor(s, 16, 64);  qq += __shfl_xor(qq, 16, 64);
                s  += __shfl_xor(s, 32, 64);  qq += __shfl_xor(qq, 32, 64);
                if (lid < 16) { float2 p; p.x = s; p.y = qq; lnp[w * 128 + trow] = p; }
            }
            __syncthreads();
            if (tid < 128) {
                float ms = 0.f, mq = 0.f;
                #pragma unroll
                for (int wv = 0; wv < 8; ++wv) {
                    float2 p = lnp[wv * 128 + tid];
                    ms += p.x; mq += p.y;
                }
                float mean = ms * 0.0078125f;
                float var  = mq * 0.0078125f - mean * mean;
                float2 m2; m2.x = mean; m2.y = rsqrtf(var + 1e-5f);
                mrp[tid] = m2;
            }
            __syncthreads();
            fx4 g4 = *(const fx4*)(ln2g + l * 128 + w * 16 + kg * 4);
            fx4 b4 = *(const fx4*)(ln2b + l * 128 + w * 16 + kg * 4);
            if (l == 1) {   // final layer: fp32 output, packed float4 stores
                float* op = out + (size_t)b * 16384;
                #pragma unroll
                for (int tt = 0; tt < 8; ++tt) {
                    int trow = tt * 16 + l15;
                    float2 m2 = mrp[trow];
                    float4 v4;
                    v4.x = (yacc[tt][0] - m2.x) * m2.y * g4[0] + b4[0];
                    v4.y = (yacc[tt][1] - m2.x) * m2.y * g4[1] + b4[1];
                    v4.z = (yacc[tt][2] - m2.x) * m2.y * g4[2] + b4[2];
                    v4.w = (yacc[tt][3] - m2.x) * m2.y * g4[3] + b4[3];
                    *(float4*)(op + (size_t)trow * 128 + w * 16 + kg * 4) = v4;
                }
            } else {
                #pragma unroll
                for (int tt = 0; tt < 8; ++tt) {
                    int trow = tt * 16 + l15;
                    float2 m2 = mrp[trow];
                    ushort4 px;
                    px.x = f2bf((yacc[tt][0] - m2.x) * m2.y * g4[0] + b4[0]);
                    px.y = f2bf((yacc[tt][1] - m2.x) * m2.y * g4[1] + b4[1]);
                    px.z = f2bf((yacc[tt][2] - m2.x) * m2.y * g4[2] + b4[2]);
                    px.w = f2bf((yacc[tt][3] - m2.x) * m2.y * g4[3] + b4[3]);
                    *(ushort4*)(xs + swz(trow, w * 16 + kg * 4)) = px;
                }
                __syncthreads();   // xs stable before next layer's Phase A
            }
        }
    }
}

// --------------------------------------------------------------------------
extern "C" void kernel_launch(void* const* d_in, const int* in_sizes, int n_in,
                              void* d_out, int out_size, void* d_ws, size_t ws_size,
                              hipStream_t stream) {
    const float* x    = (const float*)d_in[0];
    const float* mask = (const float*)d_in[1];
    const float* w_in = (const float*)d_in[2];
    const float* b_in = (const float*)d_in[3];
    const float* w_o  = (const float*)d_in[4];
    const float* b_o  = (const float*)d_in[5];
    const float* g1   = (const float*)d_in[6];
    const float* bb1  = (const float*)d_in[7];
    const float* w1   = (const float*)d_in[8];
    const float* b1   = (const float*)d_in[9];
    const float* w2   = (const float*)d_in[10];
    const float* b2   = (const float*)d_in[11];
    const float* g2   = (const float*)d_in[12];
    const float* bb2  = (const float*)d_in[13];

    unsigned short* ws = (unsigned short*)d_ws;   // bf16 weights, 786432 B
    prep_weights_bf16<<<1536, 256, 0, stream>>>(w_in, w_o, w1, w2, ws);
    fused_transformer<<<1024, 512, 0, stream>>>(
        x, mask, b_in, b_o, g1, bb1, b1, b2, g2, bb2,
        ws,                 // in_proj  [L][384][128]
        ws + 98304,         // out_w    [L][128][128]
        ws + 131072,        // ff1_w    [L][512][128]
        ws + 262144,        // ff2_w    [L][128][512]
        (float*)d_out);
}

// Round 4
// 489.583 us; speedup vs baseline: 1.0958x; 1.0958x over previous
//
#include <hip/hip_runtime.h>

// ============================================================================
// Fused 2-layer transformer encoder (B=1024, T=128, D=128, H=8, HD=16, FF=512)
// One workgroup per batch element; bf16 MFMA 16x16x32 for every matmul; fp32
// accumulation/softmax/LN. All matmuls in transposed orientation (Y^T = W*X^T)
// so C-fragments pack as ushort4 column runs.
//
// Occupancy revision 2: LDS 73 KiB (2 blocks/CU possible). Register strategy:
// do NOT force the 128-reg tier via launch_bounds(512,4) — round-3 showed the
// compiler then splits 64 arch + 64 acc and spills ~190 dwords/thread to
// scratch (+700 MB HBM traffic). Instead use (512,2) (budget 256, no spills)
// and SHAVE natural peak pressure to land <=128 total so the runtime occupancy
// calculator grants 16 waves/CU on its own:
//  - Phase A split into three sequential passes (Q, K, V): weight fragments
//    for Q/K/V are never co-live (saves ~16 regs at the peak; costs 32 extra
//    ds_read_b128 per wave per layer -- DS pipe has slack).
//  - K and V never touch LDS (producer C-layout -> consumer A-fragment is a
//    same-l15 cross-kg permutation done with __shfl on bf16-packed dwords).
//  - P -> PV handoff via the same shuffle gather (no P scratch, no lgkmcnt
//    serialization inside the q-tile loop).
//  - FF hidden aliases the q/o buffer (4 chunks of 128).
// ============================================================================

typedef __attribute__((ext_vector_type(8))) __bf16 bf16x8;
typedef __attribute__((ext_vector_type(4))) float fx4;

#define MFMA16(a, b, c) __builtin_amdgcn_mfma_f32_16x16x32_bf16((a), (b), (c), 0, 0, 0)

static __device__ __forceinline__ unsigned short f2bf(float f) {
    __bf16 b = (__bf16)f;                       // fptrunc f32->bf16, RTN-even
    return __builtin_bit_cast(unsigned short, b);
}
static __device__ __forceinline__ float bf2f(unsigned short u) {
    return (float)__builtin_bit_cast(__bf16, u);
}
static __device__ __forceinline__ unsigned pk2(float a, float b) {
    return (unsigned)f2bf(a) | ((unsigned)f2bf(b) << 16);
}
static __device__ __forceinline__ bf16x8 mk8(unsigned d0, unsigned d1,
                                             unsigned d2, unsigned d3) {
    union { unsigned u[4]; bf16x8 v; } c;
    c.u[0] = d0; c.u[1] = d1; c.u[2] = d2; c.u[3] = d3;
    return c.v;
}
// element index into a [128][128] tile, 16B-unit XOR swizzle on the row
static __device__ __forceinline__ int swz(int row, int col) {
    return (row << 7) + (col ^ ((row & 7) << 3));
}

// --------------------------------------------------------------------------
// Prep: convert all fp32 weights to bf16 into workspace.
// Segments (elements): in_proj 98304 | out 32768 | ff1 131072 | ff2 131072
// --------------------------------------------------------------------------
extern "C" __global__ void prep_weights_bf16(const float* __restrict__ w_in,
                                             const float* __restrict__ w_out,
                                             const float* __restrict__ w_ff1,
                                             const float* __restrict__ w_ff2,
                                             unsigned short* __restrict__ ws) {
    int i = blockIdx.x * 256 + threadIdx.x;     // grid covers exactly 393216
    float v;
    if (i < 98304)       v = w_in[i];
    else if (i < 131072) v = w_out[i - 98304];
    else if (i < 262144) v = w_ff1[i - 131072];
    else                 v = w_ff2[i - 262144];
    ws[i] = f2bf(v);
}

// --------------------------------------------------------------------------
// Main fused kernel. block = 512 threads = 8 waves. grid = 1024 (one per b).
// __launch_bounds__(512, 2): RA budget 256 (never spills); occupancy comes
// from actual usage -- target is natural allocation <= 128 regs.
// --------------------------------------------------------------------------
extern "C" __global__ void __launch_bounds__(512, 2)
fused_transformer(const float* __restrict__ x,
                  const float* __restrict__ mask,
                  const float* __restrict__ inp_b,
                  const float* __restrict__ out_b,
                  const float* __restrict__ ln1g, const float* __restrict__ ln1b,
                  const float* __restrict__ ff1b, const float* __restrict__ ff2b,
                  const float* __restrict__ ln2g, const float* __restrict__ ln2b,
                  const unsigned short* __restrict__ w_inp,
                  const unsigned short* __restrict__ w_out,
                  const unsigned short* __restrict__ w_ff1,
                  const unsigned short* __restrict__ w_ff2,
                  float* __restrict__ out) {
    // 73 KiB static LDS -> 2 blocks/CU (if regs <= 128)
    __shared__ __align__(16) unsigned short xs[16384];   // x / LN outputs [t][d]
    __shared__ __align__(16) unsigned short qs[16384];   // q -> o -> FF hidden
    __shared__ __align__(16) float lnbuf[2304];          // LN scratch, 9 KiB

    float2* lnp = (float2*)lnbuf;          // [8][128] {sum, sumsq}
    float2* mrp = lnp + 1024;              // [128] {mean, rstd}

    const int tid = threadIdx.x;
    const int w   = tid >> 6;        // wave 0..7 (== head in phase B)
    const int lid = tid & 63;
    const int l15 = lid & 15;
    const int kg  = lid >> 4;        // k-group 0..3
    const int b   = blockIdx.x;

    // ---- stage x[b] (fp32 global) -> xs (bf16 LDS, swizzled) ----
    const float* xb = x + (size_t)b * 16384;
    #pragma unroll
    for (int i = 0; i < 8; ++i) {
        int e = i * 2048 + tid * 4;
        float4 v4 = *(const float4*)(xb + e);
        int row = e >> 7, col = e & 127;
        ushort4 pk;
        pk.x = f2bf(v4.x); pk.y = f2bf(v4.y); pk.z = f2bf(v4.z); pk.w = f2bf(v4.w);
        *(ushort4*)(xs + swz(row, col)) = pk;
    }
    // additive key mask, key = nt*16 + l15 (per-lane, reused for both layers)
    float mreg[8];
    #pragma unroll
    for (int nt = 0; nt < 8; ++nt) mreg[nt] = mask[b * 128 + nt * 16 + l15];

    __syncthreads();

    for (int l = 0; l < 2; ++l) {
        bf16x8 kfr[8];   // K A-fragments for this wave's head (+mask slot)
        bf16x8 vfr[4];   // V^T A-fragments

        // ========== Phase A: QKV projection, three low-pressure passes ======
        {
            const unsigned short* wbase = w_inp + (size_t)l * 49152;
            // ---- pass 1: Q ----
            {
                bf16x8 wq[4];
                #pragma unroll
                for (int ks = 0; ks < 4; ++ks)
                    wq[ks] = *(const bf16x8*)(wbase + (w * 16 + l15) * 128 + ks * 32 + kg * 8);
                fx4 bq = *(const fx4*)(inp_b + l * 384 + w * 16 + kg * 4);
                #pragma unroll
                for (int mt = 0; mt < 8; ++mt) {
                    int trow = mt * 16 + l15;
                    bf16x8 xf[4];
                    #pragma unroll
                    for (int ks = 0; ks < 4; ++ks)
                        xf[ks] = *(const bf16x8*)(xs + swz(trow, ks * 32 + kg * 8));
                    fx4 aq = bq;
                    #pragma unroll
                    for (int ks = 0; ks < 4; ++ks)
                        aq = MFMA16(wq[ks], xf[ks], aq);   // Q^T = Wq * X^T
                    ushort4 pq;  // q pre-scaled by 1/sqrt(HD) = 0.25 (exact in bf16)
                    pq.x = f2bf(aq[0] * 0.25f); pq.y = f2bf(aq[1] * 0.25f);
                    pq.z = f2bf(aq[2] * 0.25f); pq.w = f2bf(aq[3] * 0.25f);
                    *(ushort4*)(qs + swz(trow, w * 16 + kg * 4)) = pq;
                }
            }
            // ---- pass 2: K -> registers (cross-kg gather) ----
            {
                bf16x8 wk[4];
                #pragma unroll
                for (int ks = 0; ks < 4; ++ks)
                    wk[ks] = *(const bf16x8*)(wbase + (128 + w * 16 + l15) * 128 + ks * 32 + kg * 8);
                fx4 bk = *(const fx4*)(inp_b + l * 384 + 128 + w * 16 + kg * 4);
                const int sk = ((2 * kg) & 3) * 16 + l15;   // gather src (kg<2 valid)
                #pragma unroll
                for (int mt = 0; mt < 8; ++mt) {
                    int trow = mt * 16 + l15;
                    bf16x8 xf[4];
                    #pragma unroll
                    for (int ks = 0; ks < 4; ++ks)
                        xf[ks] = *(const bf16x8*)(xs + swz(trow, ks * 32 + kg * 8));
                    fx4 ak = bk;
                    #pragma unroll
                    for (int ks = 0; ks < 4; ++ks)
                        ak = MFMA16(wk[ks], xf[ks], ak);   // K^T = Wk * X^T
                    // pack 4 f32 -> 2 bf16-pair dwords, cross-kg gather
                    unsigned p0 = pk2(ak[0], ak[1]), p1 = pk2(ak[2], ak[3]);
                    unsigned d0 = __shfl(p0, sk, 64),      d1 = __shfl(p1, sk, 64);
                    unsigned d2 = __shfl(p0, sk + 16, 64), d3 = __shfl(p1, sk + 16, 64);
                    if (kg == 2)      { bf16x8 f = {}; f[0] = (__bf16)mreg[mt]; kfr[mt] = f; }
                    else if (kg == 3) { bf16x8 f = {}; kfr[mt] = f; }
                    else              kfr[mt] = mk8(d0, d1, d2, d3);
                }
            }
            // ---- pass 3: V -> registers ----
            {
                bf16x8 wv[4];
                #pragma unroll
                for (int ks = 0; ks < 4; ++ks)
                    wv[ks] = *(const bf16x8*)(wbase + (256 + w * 16 + l15) * 128 + ks * 32 + kg * 8);
                float bv = inp_b[l * 384 + 256 + w * 16 + l15];
                const int sv = (2 * (kg & 1)) * 16 + l15;
                #pragma unroll
                for (int mt = 0; mt < 8; ++mt) {
                    int trow = mt * 16 + l15;
                    bf16x8 xf[4];
                    #pragma unroll
                    for (int ks = 0; ks < 4; ++ks)
                        xf[ks] = *(const bf16x8*)(xs + swz(trow, ks * 32 + kg * 8));
                    fx4 av = {bv, bv, bv, bv};
                    #pragma unroll
                    for (int ks = 0; ks < 4; ++ks)
                        av = MFMA16(xf[ks], wv[ks], av);   // V = X * Wv^T
                    unsigned p0 = pk2(av[0], av[1]), p1 = pk2(av[2], av[3]);
                    unsigned d0 = __shfl(p0, sv, 64),      d1 = __shfl(p1, sv, 64);
                    unsigned d2 = __shfl(p0, sv + 16, 64), d3 = __shfl(p1, sv + 16, 64);
                    if ((kg >> 1) == (mt & 1)) vfr[mt >> 1] = mk8(d0, d1, d2, d3);
                }
            }
        }
        // own-wave q write -> read; drain DS queue (no cross-wave dependency)
        asm volatile("s_waitcnt lgkmcnt(0)" ::: "memory");

        // ========== Phase B: attention, wave w == head h (no barriers) ======
        {
            const int h = w;
            const int sp = (2 * (kg & 1)) * 16 + l15;   // P gather src base
            for (int qt = 0; qt < 8; ++qt) {
                int qrow = qt * 16 + l15;
                bf16x8 qf = {};
                if (kg < 2) qf = *(const bf16x8*)(qs + swz(qrow, h * 16 + kg * 8));
                else if (kg == 2) qf[0] = (__bf16)1.0f;   // ones column -> adds mask
                // S^T tile: lane l15 = query, 32 regs = keys (scaled+masked)
                fx4 sc[8];
                #pragma unroll
                for (int kt = 0; kt < 8; ++kt) {
                    fx4 z = {0.f, 0.f, 0.f, 0.f};
                    sc[kt] = MFMA16(kfr[kt], qf, z);
                }
                // per-lane softmax over 32 regs + 2 shuffles across kg
                float mx = -3.0e38f;
                #pragma unroll
                for (int kt = 0; kt < 8; ++kt)
                    #pragma unroll
                    for (int r = 0; r < 4; ++r) mx = fmaxf(mx, sc[kt][r]);
                mx = fmaxf(mx, __shfl_xor(mx, 16, 64));
                mx = fmaxf(mx, __shfl_xor(mx, 32, 64));
                float sm = 0.f;
                #pragma unroll
                for (int kt = 0; kt < 8; ++kt)
                    #pragma unroll
                    for (int r = 0; r < 4; ++r) {
                        float e = __expf(sc[kt][r] - mx);
                        sc[kt][r] = e;
                        sm += e;
                    }
                sm += __shfl_xor(sm, 16, 64);
                sm += __shfl_xor(sm, 32, 64);
                float inv = 1.f / sm;
                // PV: per 32-key step, gather P^T fragment via 8 shuffles
                fx4 oacc = {0.f, 0.f, 0.f, 0.f};
                #pragma unroll
                for (int s = 0; s < 4; ++s) {
                    unsigned pA0 = pk2(sc[2*s][0] * inv,   sc[2*s][1] * inv);
                    unsigned pA1 = pk2(sc[2*s][2] * inv,   sc[2*s][3] * inv);
                    unsigned pB0 = pk2(sc[2*s+1][0] * inv, sc[2*s+1][1] * inv);
                    unsigned pB1 = pk2(sc[2*s+1][2] * inv, sc[2*s+1][3] * inv);
                    unsigned a0 = __shfl(pA0, sp, 64),      a1 = __shfl(pA1, sp, 64);
                    unsigned a2 = __shfl(pA0, sp + 16, 64), a3 = __shfl(pA1, sp + 16, 64);
                    unsigned b0 = __shfl(pB0, sp, 64),      b1 = __shfl(pB1, sp, 64);
                    unsigned b2 = __shfl(pB0, sp + 16, 64), b3 = __shfl(pB1, sp + 16, 64);
                    bf16x8 pf = (kg & 2) ? mk8(b0, b1, b2, b3) : mk8(a0, a1, a2, a3);
                    oacc = MFMA16(vfr[s], pf, oacc);        // O^T = V^T * P^T
                }
                // o tile packs as [t][d] ushort4; overwrites q cols of this qt
                ushort4 po;
                po.x = f2bf(oacc[0]); po.y = f2bf(oacc[1]);
                po.z = f2bf(oacc[2]); po.w = f2bf(oacc[3]);
                *(ushort4*)(qs + swz(qrow, h * 16 + kg * 4)) = po;
            }
        }
        __syncthreads();

        // ========= Phase C: out-proj (transposed) + residual + LN1 ==========
        {
            bf16x8 wof[4];
            #pragma unroll
            for (int ks = 0; ks < 4; ++ks)
                wof[ks] = *(const bf16x8*)(w_out + (size_t)(l * 128 + w * 16 + l15) * 128
                                           + ks * 32 + kg * 8);
            fx4 ob4 = *(const fx4*)(out_b + l * 128 + w * 16 + kg * 4);
            fx4 acc[8];
            #pragma unroll
            for (int tt = 0; tt < 8; ++tt) {
                int trow = tt * 16 + l15;
                fx4 a = {0.f, 0.f, 0.f, 0.f};
                #pragma unroll
                for (int ks = 0; ks < 4; ++ks) {
                    bf16x8 of = *(const bf16x8*)(qs + swz(trow, ks * 32 + kg * 8));
                    a = MFMA16(wof[ks], of, a);     // OUT^T = Wout * O^T
                }
                ushort4 rx = *(const ushort4*)(xs + swz(trow, w * 16 + kg * 4));
                a[0] += ob4[0] + bf2f(rx.x); a[1] += ob4[1] + bf2f(rx.y);
                a[2] += ob4[2] + bf2f(rx.z); a[3] += ob4[3] + bf2f(rx.w);
                acc[tt] = a;
                float s  = a[0] + a[1] + a[2] + a[3];
                float qq = a[0]*a[0] + a[1]*a[1] + a[2]*a[2] + a[3]*a[3];
                s  += __shfl_xor(s, 16, 64);  qq += __shfl_xor(qq, 16, 64);
                s  += __shfl_xor(s, 32, 64);  qq += __shfl_xor(qq, 32, 64);
                if (lid < 16) { float2 p; p.x = s; p.y = qq; lnp[w * 128 + trow] = p; }
            }
            __syncthreads();
            if (tid < 128) {
                float ms = 0.f, mq = 0.f;
                #pragma unroll
                for (int wv = 0; wv < 8; ++wv) {
                    float2 p = lnp[wv * 128 + tid];
                    ms += p.x; mq += p.y;
                }
                float mean = ms * 0.0078125f;
                float var  = mq * 0.0078125f - mean * mean;
                float2 m2; m2.x = mean; m2.y = rsqrtf(var + 1e-5f);
                mrp[tid] = m2;
            }
            __syncthreads();
            fx4 g4 = *(const fx4*)(ln1g + l * 128 + w * 16 + kg * 4);
            fx4 b4 = *(const fx4*)(ln1b + l * 128 + w * 16 + kg * 4);
            #pragma unroll
            for (int tt = 0; tt < 8; ++tt) {
                int trow = tt * 16 + l15;
                float2 m2 = mrp[trow];
                ushort4 px;
                px.x = f2bf((acc[tt][0] - m2.x) * m2.y * g4[0] + b4[0]);
                px.y = f2bf((acc[tt][1] - m2.x) * m2.y * g4[1] + b4[1]);
                px.z = f2bf((acc[tt][2] - m2.x) * m2.y * g4[2] + b4[2]);
                px.w = f2bf((acc[tt][3] - m2.x) * m2.y * g4[3] + b4[3]);
                *(ushort4*)(xs + swz(trow, w * 16 + kg * 4)) = px;
            }
        }
        __syncthreads();

        // ======== Phase D: FF, 4 K-chunks of 128; hidden aliases qs =========
        fx4 yacc[8];
        {
            fx4 z = {0.f, 0.f, 0.f, 0.f};
            #pragma unroll
            for (int tt = 0; tt < 8; ++tt) yacc[tt] = z;
        }
        #pragma unroll 1
        for (int c = 0; c < 4; ++c) {
            {   // FF1: H^T = W1 * X^T, + bias + relu -> qs (packed)
                bf16x8 w1f[4];
                int frow = l * 512 + c * 128 + w * 16;
                #pragma unroll
                for (int ks = 0; ks < 4; ++ks)
                    w1f[ks] = *(const bf16x8*)(w_ff1 + (size_t)(frow + l15) * 128
                                               + ks * 32 + kg * 8);
                fx4 b1f = *(const fx4*)(ff1b + frow + kg * 4);
                #pragma unroll
                for (int tt = 0; tt < 8; ++tt) {
                    int trow = tt * 16 + l15;
                    bf16x8 xf[4];
                    #pragma unroll
                    for (int ks = 0; ks < 4; ++ks)
                        xf[ks] = *(const bf16x8*)(xs + swz(trow, ks * 32 + kg * 8));
                    fx4 a = b1f;
                    #pragma unroll
                    for (int ks = 0; ks < 4; ++ks)
                        a = MFMA16(w1f[ks], xf[ks], a);
                    ushort4 ph;
                    ph.x = f2bf(fmaxf(a[0], 0.f)); ph.y = f2bf(fmaxf(a[1], 0.f));
                    ph.z = f2bf(fmaxf(a[2], 0.f)); ph.w = f2bf(fmaxf(a[3], 0.f));
                    *(ushort4*)(qs + swz(trow, w * 16 + kg * 4)) = ph;
                }
            }
            __syncthreads();
            {   // FF2 partial accumulate: Y^T = W2 * H^T
                bf16x8 w2f[4];
                #pragma unroll
                for (int k8 = 0; k8 < 4; ++k8)
                    w2f[k8] = *(const bf16x8*)(w_ff2 + (size_t)(l * 128 + w * 16 + l15) * 512
                                               + c * 128 + k8 * 32 + kg * 8);
                #pragma unroll
                for (int tt = 0; tt < 8; ++tt) {
                    int trow = tt * 16 + l15;
                    #pragma unroll
                    for (int k8 = 0; k8 < 4; ++k8) {
                        bf16x8 hf = *(const bf16x8*)(qs + swz(trow, k8 * 32 + kg * 8));
                        yacc[tt] = MFMA16(w2f[k8], hf, yacc[tt]);
                    }
                }
            }
            if (c < 3) __syncthreads();   // protect hidden before next chunk
        }

        // ========= Phase E: + bias + residual + LayerNorm2 (+ output) =======
        {
            fx4 fb4 = *(const fx4*)(ff2b + l * 128 + w * 16 + kg * 4);
            #pragma unroll
            for (int tt = 0; tt < 8; ++tt) {
                int trow = tt * 16 + l15;
                ushort4 rx = *(const ushort4*)(xs + swz(trow, w * 16 + kg * 4));
                yacc[tt][0] += fb4[0] + bf2f(rx.x);
                yacc[tt][1] += fb4[1] + bf2f(rx.y);
                yacc[tt][2] += fb4[2] + bf2f(rx.z);
                yacc[tt][3] += fb4[3] + bf2f(rx.w);
                fx4 a = yacc[tt];
                float s  = a[0] + a[1] + a[2] + a[3];
                float qq = a[0]*a[0] + a[1]*a[1] + a[2]*a[2] + a[3]*a[3];
                s  += __shfl_xor(s, 16, 64);  qq += __shfl_xor(qq, 16, 64);
                s  += __shfl_xor(s, 32, 64);  qq += __shfl_xor(qq, 32, 64);
                if (lid < 16) { float2 p; p.x = s; p.y = qq; lnp[w * 128 + trow] = p; }
            }
            __syncthreads();
            if (tid < 128) {
                float ms = 0.f, mq = 0.f;
                #pragma unroll
                for (int wv = 0; wv < 8; ++wv) {
                    float2 p = lnp[wv * 128 + tid];
                    ms += p.x; mq += p.y;
                }
                float mean = ms * 0.0078125f;
                float var  = mq * 0.0078125f - mean * mean;
                float2 m2; m2.x = mean; m2.y = rsqrtf(var + 1e-5f);
                mrp[tid] = m2;
            }
            __syncthreads();
            fx4 g4 = *(const fx4*)(ln2g + l * 128 + w * 16 + kg * 4);
            fx4 b4 = *(const fx4*)(ln2b + l * 128 + w * 16 + kg * 4);
            if (l == 1) {   // final layer: fp32 output, packed float4 stores
                float* op = out + (size_t)b * 16384;
                #pragma unroll
                for (int tt = 0; tt < 8; ++tt) {
                    int trow = tt * 16 + l15;
                    float2 m2 = mrp[trow];
                    float4 v4;
                    v4.x = (yacc[tt][0] - m2.x) * m2.y * g4[0] + b4[0];
                    v4.y = (yacc[tt][1] - m2.x) * m2.y * g4[1] + b4[1];
                    v4.z = (yacc[tt][2] - m2.x) * m2.y * g4[2] + b4[2];
                    v4.w = (yacc[tt][3] - m2.x) * m2.y * g4[3] + b4[3];
                    *(float4*)(op + (size_t)trow * 128 + w * 16 + kg * 4) = v4;
                }
            } else {
                #pragma unroll
                for (int tt = 0; tt < 8; ++tt) {
                    int trow = tt * 16 + l15;
                    float2 m2 = mrp[trow];
                    ushort4 px;
                    px.x = f2bf((yacc[tt][0] - m2.x) * m2.y * g4[0] + b4[0]);
                    px.y = f2bf((yacc[tt][1] - m2.x) * m2.y * g4[1] + b4[1]);
                    px.z = f2bf((yacc[tt][2] - m2.x) * m2.y * g4[2] + b4[2]);
                    px.w = f2bf((yacc[tt][3] - m2.x) * m2.y * g4[3] + b4[3]);
                    *(ushort4*)(xs + swz(trow, w * 16 + kg * 4)) = px;
                }
                __syncthreads();   // xs stable before next layer's Phase A
            }
        }
    }
}

// --------------------------------------------------------------------------
extern "C" void kernel_launch(void* const* d_in, const int* in_sizes, int n_in,
                              void* d_out, int out_size, void* d_ws, size_t ws_size,
                              hipStream_t stream) {
    const float* x    = (const float*)d_in[0];
    const float* mask = (const float*)d_in[1];
    const float* w_in = (const float*)d_in[2];
    const float* b_in = (const float*)d_in[3];
    const float* w_o  = (const float*)d_in[4];
    const float* b_o  = (const float*)d_in[5];
    const float* g1   = (const float*)d_in[6];
    const float* bb1  = (const float*)d_in[7];
    const float* w1   = (const float*)d_in[8];
    const float* b1   = (const float*)d_in[9];
    const float* w2   = (const float*)d_in[10];
    const float* b2   = (const float*)d_in[11];
    const float* g2   = (const float*)d_in[12];
    const float* bb2  = (const float*)d_in[13];

    unsigned short* ws = (unsigned short*)d_ws;   // bf16 weights, 786432 B
    prep_weights_bf16<<<1536, 256, 0, stream>>>(w_in, w_o, w1, w2, ws);
    fused_transformer<<<1024, 512, 0, stream>>>(
        x, mask, b_in, b_o, g1, bb1, b1, b2, g2, bb2,
        ws,                 // in_proj  [L][384][128]
        ws + 98304,         // out_w    [L][128][128]
        ws + 131072,        // ff1_w    [L][512][128]
        ws + 262144,        // ff2_w    [L][128][512]
        (float*)d_out);
}